// Round 1
// baseline (502.273 us; speedup 1.0000x reference)
//
#include <hip/hip_runtime.h>
#include <stdint.h>

// NARM fused pipeline v5 for MI355X (gfx950).
//   k_prep : zero carry slots + cum; cast A1/A2 -> bf16
//   k_gi   : prologue GEMM: gi(chunk 0) = x@Wih + bias, stored bf16 in MFMA C-frag order
//   k_scan : grid 256 = 128 scan blocks (h-side recurrence only, 12 MFMA/wave/step,
//            gi loaded from workspace) + 128 gemm blocks (compute gi for chunk c+1,
//            concurrent on the otherwise-idle CUs). LDS pad >80KB forces 1 block/CU.
//   k_score: grid (tc,4), 256 thr; A1/A2 bf16 staged once per block
//   k_cum  : LDS-staged cumsum of score*h_l, capture t in [L_b-4, L_b-1], +h_g

typedef __attribute__((ext_vector_type(8))) short short8;
typedef __attribute__((ext_vector_type(4))) float float4v;

// exec+LDS barrier without the full vmcnt drain of __syncthreads()
#define LDS_BARRIER() asm volatile("s_waitcnt lgkmcnt(0)\n\ts_barrier" ::: "memory")

__device__ inline float bf2f(unsigned short u){
  union { unsigned int i; float f; } v; v.i = ((unsigned int)u) << 16; return v.f;
}
__device__ inline float u2f(unsigned int b){
  union { unsigned int i; float f; } v; v.i = b; return v.f;
}
__device__ inline unsigned short f2bf(float f){
  union { float f; unsigned int i; } v; v.f = f;
  unsigned int x = v.i;
  return (unsigned short)((x + 0x7fffu + ((x >> 16) & 1u)) >> 16);
}
__device__ inline unsigned int pack2(float a, float b){
  return (unsigned int)f2bf(a) | ((unsigned int)f2bf(b) << 16);
}
__device__ inline float sigm(float x){ return __builtin_amdgcn_rcpf(1.0f + __expf(-x)); }

// ---------------- K0: prep ----------------
__global__ void k_prep(unsigned short* hl_slot, unsigned short* hg_slot, float* cum,
                       const float* A1, const float* A2, unsigned short* a12)
{
  int i = blockIdx.x * blockDim.x + threadIdx.x;   // grid 512*256 = 131072
  hl_slot[i] = 0;
  hg_slot[i] = 0;
  cum[i] = 0.0f;
  if (i < 32768) {
    a12[i] = f2bf((i < 16384) ? A1[i] : A2[i - 16384]);
  }
}

// ---------------- gi GEMM body ----------------
// One block = one (batch-group, gru). Computes gi[t][bid2][gate][tid][4rows] bf16,
// biases folded (r,z: bih+bhh; n: bih only). Layout = MFMA C-fragment order so the
// scan reads its 12 values as 3 uint2 loads.
__device__ __forceinline__ void gi_gemm(
    const float* __restrict__ x,
    const float* __restrict__ Wih, const float* __restrict__ bih,
    const float* __restrict__ bhh,
    unsigned short* __restrict__ gi, int gtc, int t0g, int bid2, int tid,
    unsigned short (*xbuf)[16][136])
{
  int w = tid >> 6, L = tid & 63, l15 = L & 15, q = L >> 4;
  int b0 = (bid2 >> 1) * 16;
  int col = w * 16 + l15;

  short8 Wi[3][4];
  #pragma unroll
  for (int G = 0; G < 3; G++) {
    int row = G * 128 + col;
    #pragma unroll
    for (int kf = 0; kf < 4; kf++) {
      const float4* p0 = (const float4*)(Wih + (size_t)row * 128 + kf * 32 + q * 8);
      float4 a0 = p0[0], a1 = p0[1];
      short8 si;
      si[0]=(short)f2bf(a0.x); si[1]=(short)f2bf(a0.y); si[2]=(short)f2bf(a0.z); si[3]=(short)f2bf(a0.w);
      si[4]=(short)f2bf(a1.x); si[5]=(short)f2bf(a1.y); si[6]=(short)f2bf(a1.z); si[7]=(short)f2bf(a1.w);
      Wi[G][kf] = si;
    }
  }
  float bias0 = bih[col]       + bhh[col];
  float bias1 = bih[128 + col] + bhh[128 + col];
  float bias2 = bih[256 + col];              // bhh_n stays inside r*( ) in the scan

  int xrow = tid >> 5, xc4 = (tid & 31) * 4;
  {
    float4 x0 = ((const float4*)(x + ((size_t)t0g * 1024 + b0) * 128))[tid];
    *(uint2*)&xbuf[0][xrow][xc4] = make_uint2(pack2(x0.x, x0.y), pack2(x0.z, x0.w));
  }
  int tn = t0g + (gtc > 1 ? 1 : 0);
  float4 xr = ((const float4*)(x + ((size_t)tn * 1024 + b0) * 128))[tid];
  __syncthreads();

  int cur = 0;
  for (int s = 0; s < gtc; s++) {
    short8 Ax[4];
    #pragma unroll
    for (int kf = 0; kf < 4; kf++) Ax[kf] = *(const short8*)&xbuf[cur][l15][kf * 32 + q * 8];

    if (s + 1 < gtc) {
      *(uint2*)&xbuf[cur ^ 1][xrow][xc4] = make_uint2(pack2(xr.x, xr.y), pack2(xr.z, xr.w));
      int t2 = t0g + (s + 2 < gtc ? s + 2 : gtc - 1);
      xr = ((const float4*)(x + ((size_t)t2 * 1024 + b0) * 128))[tid];
    }

    float4v ar = (float4v){0.f,0.f,0.f,0.f}, az = ar, an = ar;
    #pragma unroll
    for (int kf = 0; kf < 4; kf++) ar = __builtin_amdgcn_mfma_f32_16x16x32_bf16(Ax[kf], Wi[0][kf], ar, 0,0,0);
    #pragma unroll
    for (int kf = 0; kf < 4; kf++) az = __builtin_amdgcn_mfma_f32_16x16x32_bf16(Ax[kf], Wi[1][kf], az, 0,0,0);
    #pragma unroll
    for (int kf = 0; kf < 4; kf++) an = __builtin_amdgcn_mfma_f32_16x16x32_bf16(Ax[kf], Wi[2][kf], an, 0,0,0);

    uint2* outp = (uint2*)(gi + ((size_t)s * 128 + bid2) * 6144) + tid;
    outp[0]    = make_uint2(pack2(ar[0] + bias0, ar[1] + bias0), pack2(ar[2] + bias0, ar[3] + bias0));
    outp[512]  = make_uint2(pack2(az[0] + bias1, az[1] + bias1), pack2(az[2] + bias1, az[3] + bias1));
    outp[1024] = make_uint2(pack2(an[0] + bias2, an[1] + bias2), pack2(an[2] + bias2, an[3] + bias2));

    LDS_BARRIER();
    cur ^= 1;
  }
}

// prologue: gi for chunk 0
__global__ __launch_bounds__(512, 2) void k_gi(
    const float* __restrict__ x,
    const float* __restrict__ Wih_g, const float* __restrict__ bih_g, const float* __restrict__ bhh_g,
    const float* __restrict__ Wih_l, const float* __restrict__ bih_l, const float* __restrict__ bhh_l,
    unsigned short* __restrict__ gi, int tcg)
{
  __shared__ __align__(16) unsigned short xbuf[2][16][136];
  __shared__ unsigned long long ldspad[9400];        // force 1 block/CU (LDS > 80KB)
  int tid = threadIdx.x;
  if (tcg == 0) ldspad[tid] = 0;                     // never taken; keeps pad alive
  int bid = blockIdx.x;
  const float* Wih = (bid & 1) ? Wih_l : Wih_g;
  const float* bih = (bid & 1) ? bih_l : bih_g;
  const float* bhh = (bid & 1) ? bhh_l : bhh_g;
  gi_gemm(x, Wih, bih, bhh, gi, tcg, 0, bid, tid, xbuf);
}

// ---------------- K1: fused scan + next-chunk GEMM ----------------
// grid 256: blocks 0..127 = scan (64 batch-groups x 2 GRUs), blocks 128..255 = gemm.
__global__ __launch_bounds__(512, 2) void k_scan(
    const float* __restrict__ x,
    const float* __restrict__ Whh_g, const float* __restrict__ bhh_g,
    const float* __restrict__ Whh_l, const float* __restrict__ bhh_l,
    const float* __restrict__ Wih_g, const float* __restrict__ bih_g,
    const float* __restrict__ Wih_l, const float* __restrict__ bih_l,
    unsigned short* __restrict__ hl_seq, unsigned short* __restrict__ hg_seq,
    const unsigned short* __restrict__ gi_rd, unsigned short* __restrict__ gi_wr,
    int tc, int t0, int gtc, int t0g)
{
  __shared__ __align__(16) unsigned short hbuf[2][16][136];
  __shared__ __align__(16) unsigned short xbuf[2][16][136];
  __shared__ unsigned long long ldspad[9400];        // force 1 block/CU (LDS > 80KB)
  int tid = threadIdx.x;
  if (tc == 0) ldspad[tid] = 0;                      // never taken; keeps pad alive
  int bid = blockIdx.x;

  if (bid >= 128) {                                  // -------- gemm half --------
    if (gtc > 0) {
      int bid2 = bid - 128;
      const float* Wih = (bid2 & 1) ? Wih_l : Wih_g;
      const float* bih = (bid2 & 1) ? bih_l : bih_g;
      const float* bhh = (bid2 & 1) ? bhh_l : bhh_g;
      gi_gemm(x, Wih, bih, bhh, gi_wr, gtc, t0g, bid2, tid, xbuf);
    }
    return;
  }

  // -------- scan half --------
  int w = tid >> 6, L = tid & 63, l15 = L & 15, q = L >> 4;
  int gru = bid & 1;                 // 0 = g, 1 = l
  int b0 = (bid >> 1) * 16;
  const float* Whh = gru ? Whh_l : Whh_g;
  const float* bhh = gru ? bhh_l : bhh_g;
  unsigned short* myseq = gru ? hl_seq : hg_seq;

  int col = w * 16 + l15;

  short8 Wh[3][4];
  #pragma unroll
  for (int G = 0; G < 3; G++) {
    int row = G * 128 + col;
    #pragma unroll
    for (int kf = 0; kf < 4; kf++) {
      const float4* p1 = (const float4*)(Whh + (size_t)row * 128 + kf * 32 + q * 8);
      float4 b0f = p1[0], b1f = p1[1];
      short8 sh;
      sh[0]=(short)f2bf(b0f.x); sh[1]=(short)f2bf(b0f.y); sh[2]=(short)f2bf(b0f.z); sh[3]=(short)f2bf(b0f.w);
      sh[4]=(short)f2bf(b1f.x); sh[5]=(short)f2bf(b1f.y); sh[6]=(short)f2bf(b1f.z); sh[7]=(short)f2bf(b1f.w);
      Wh[G][kf] = sh;
    }
  }
  float bnh = bhh[256 + col];

  // init h from carry slot (zeroed by k_prep for chunk 0)
  float hold[4];
  #pragma unroll
  for (int r = 0; r < 4; r++) {
    int m = q * 4 + r;
    unsigned short u = myseq[((size_t)(tc - 1) * 1024 + b0 + m) * 128 + col];
    hold[r] = bf2f(u);
    hbuf[0][m][col] = u;
  }

  // gi pointers: [t][bid][gate][tid] as uint2 (4 bf16 = 4 rows of one gate)
  const uint2* gbase = (const uint2*)gi_rd + (size_t)bid * 1536 + tid;
  uint2 gc0 = gbase[0], gc1 = gbase[512], gc2 = gbase[1024];
  const uint2* gptr = gbase + 196608;   // t_local = 1 (last-step prefetch overreads
                                        // one slice: gi buffers precede hl -> safe)
  __syncthreads();

  // hoisted output pointer: stores at opq[r*128] with immediate offsets
  unsigned short* opq = myseq + ((size_t)(b0 + q * 4)) * 128 + col;

  auto step = [&](int pin, int pout) {
    short8 Ah[4];
    #pragma unroll
    for (int kf = 0; kf < 4; kf++) Ah[kf] = *(const short8*)&hbuf[pin][l15][kf * 32 + q * 8];

    // prefetch gi(s+1)
    uint2 gn0 = gptr[0], gn1 = gptr[512], gn2 = gptr[1024];
    gptr += 196608;

    // three independent 4-deep MFMA chains (h-side only)
    float4v rh = (float4v){0.f,0.f,0.f,0.f}, zh = rh, nh = rh;
    #pragma unroll
    for (int kf = 0; kf < 4; kf++) rh = __builtin_amdgcn_mfma_f32_16x16x32_bf16(Ah[kf], Wh[0][kf], rh, 0,0,0);
    #pragma unroll
    for (int kf = 0; kf < 4; kf++) zh = __builtin_amdgcn_mfma_f32_16x16x32_bf16(Ah[kf], Wh[1][kf], zh, 0,0,0);
    #pragma unroll
    for (int kf = 0; kf < 4; kf++) nh = __builtin_amdgcn_mfma_f32_16x16x32_bf16(Ah[kf], Wh[2][kf], nh, 0,0,0);

    // unpack precomputed x-side gate constants (biases folded)
    float cr[4], cz[4], cn[4];
    cr[0]=u2f(gc0.x<<16); cr[1]=u2f(gc0.x & 0xffff0000u);
    cr[2]=u2f(gc0.y<<16); cr[3]=u2f(gc0.y & 0xffff0000u);
    cz[0]=u2f(gc1.x<<16); cz[1]=u2f(gc1.x & 0xffff0000u);
    cz[2]=u2f(gc1.y<<16); cz[3]=u2f(gc1.y & 0xffff0000u);
    cn[0]=u2f(gc2.x<<16); cn[1]=u2f(gc2.x & 0xffff0000u);
    cn[2]=u2f(gc2.y<<16); cn[3]=u2f(gc2.y & 0xffff0000u);

    // gates: shared-rcp sigmoid pair + exp-based tanh
    #pragma unroll
    for (int r = 0; r < 4; r++) {
      float er = __expf(-(rh[r] + cr[r]));
      float ez = __expf(-(zh[r] + cz[r]));
      float pr = 1.0f + er, pz = 1.0f + ez;
      float inv = __builtin_amdgcn_rcpf(pr * pz);
      float rr = pz * inv;                  // = 1/(1+er)
      float zz = pr * inv;                  // = 1/(1+ez)
      float y  = cn[r] + rr * (nh[r] + bnh);
      float em = __expf(-2.0f * y);
      float nn = 2.0f * __builtin_amdgcn_rcpf(1.0f + em) - 1.0f;   // tanh(y)
      float hn = nn + zz * (hold[r] - nn);
      hold[r] = hn;
      unsigned short hu = f2bf(hn);
      hbuf[pout][q * 4 + r][col] = hu;
      opq[r * 128] = hu;
    }
    gc0 = gn0; gc1 = gn1; gc2 = gn2;
    opq += 131072;                          // advance one timestep (1024*128)
    LDS_BARRIER();
  };

  int s = 0;
  for (; s + 1 < tc; s += 2) { step(0, 1); step(1, 0); }
  if (s < tc) step(0, 1);
}

// ---------------- K2: attention score ----------------
// grid (tc, 4), block 256 (4 waves); each wave: 4 b-tiles of 16 rows.
__global__ __launch_bounds__(256) void k_score(const unsigned short* __restrict__ hl_seq,
                                               const unsigned short* __restrict__ hg_seq,
                                               const unsigned short* __restrict__ a12,
                                               const float* __restrict__ v1,
                                               float* __restrict__ score, int tc)
{
  __shared__ __align__(16) unsigned short M1[128][136];
  __shared__ __align__(16) unsigned short M2[128][136];
  int tid = threadIdx.x;
  int w = tid >> 6, L = tid & 63;
  int l15 = L & 15, q = L >> 4;
  int s = blockIdx.x;
  int bq = blockIdx.y * 256;

  // stage A1, A2 (bf16, pre-cast by k_prep) once: 4096 short8 over 256 thr
  #pragma unroll
  for (int it = 0; it < 8; it++) {
    int f8 = it * 256 + tid;                 // 0..2047
    *(short8*)&M1[f8 >> 4][(f8 & 15) * 8] = *(const short8*)(a12 + (size_t)f8 * 8);
    *(short8*)&M2[f8 >> 4][(f8 & 15) * 8] = *(const short8*)(a12 + 16384 + (size_t)f8 * 8);
  }
  __syncthreads();

  float v1v[8];
  #pragma unroll
  for (int nt = 0; nt < 8; nt++) v1v[nt] = v1[nt * 16 + l15];

  // 4 b-tiles per wave, 1-deep fragment prefetch
  short8 Fl[4], Fg[4], Pl[4], Pg[4];
  {
    size_t base = ((size_t)s * 1024 + bq + (size_t)w * 16 + l15) * 128;
    #pragma unroll
    for (int kf = 0; kf < 4; kf++) {
      Fl[kf] = *(const short8*)(hl_seq + base + kf * 32 + q * 8);
      Fg[kf] = *(const short8*)(hg_seq + base + kf * 32 + q * 8);
    }
  }
  #pragma unroll
  for (int it = 0; it < 4; it++) {
    int b0 = bq + (it * 4 + w) * 16;
    if (it + 1 < 4) {
      size_t base = ((size_t)s * 1024 + bq + (size_t)((it + 1) * 4 + w) * 16 + l15) * 128;
      #pragma unroll
      for (int kf = 0; kf < 4; kf++) {
        Pl[kf] = *(const short8*)(hl_seq + base + kf * 32 + q * 8);
        Pg[kf] = *(const short8*)(hg_seq + base + kf * 32 + q * 8);
      }
    }
    float4v acc[8];
    #pragma unroll
    for (int nt = 0; nt < 8; nt++) {
      float4v a = (float4v){0.f, 0.f, 0.f, 0.f};
      #pragma unroll
      for (int kf = 0; kf < 4; kf++)
        a = __builtin_amdgcn_mfma_f32_16x16x32_bf16(
            Fl[kf], *(const short8*)&M1[nt * 16 + l15][kf * 32 + q * 8], a, 0, 0, 0);
      #pragma unroll
      for (int kf = 0; kf < 4; kf++)
        a = __builtin_amdgcn_mfma_f32_16x16x32_bf16(
            Fg[kf], *(const short8*)&M2[nt * 16 + l15][kf * 32 + q * 8], a, 0, 0, 0);
      acc[nt] = a;
    }
    float p4[4];
    #pragma unroll
    for (int r = 0; r < 4; r++) {
      float sum = 0.f;
      #pragma unroll
      for (int nt = 0; nt < 8; nt++) sum += v1v[nt] * sigm(acc[nt][r]);
      sum += __shfl_xor(sum, 1, 16);
      sum += __shfl_xor(sum, 2, 16);
      sum += __shfl_xor(sum, 4, 16);
      sum += __shfl_xor(sum, 8, 16);
      p4[r] = sum;
    }
    if (l15 == 0) {
      #pragma unroll
      for (int r = 0; r < 4; r++)
        score[(size_t)(b0 + q * 4 + r) * tc + s] = p4[r];   // layout [b][tc]
    }
    #pragma unroll
    for (int kf = 0; kf < 4; kf++) { Fl[kf] = Pl[kf]; Fg[kf] = Pg[kf]; }
  }
}

// ---------------- K3: cumsum + capture (LDS-staged) ----------------
// grid 512, block 256: 2 batch rows/block, thread = (b2, j)
__global__ __launch_bounds__(256) void k_cum(const float* __restrict__ score,
                                             const unsigned short* __restrict__ hl_seq,
                                             const unsigned short* __restrict__ hg_seq,
                                             const int* __restrict__ lengths,
                                             float* __restrict__ cum,
                                             float* __restrict__ out, int tc, int t0)
{
  __shared__ __align__(16) unsigned short hlL[100 * 256];  // [s_seg][b2*128+j]
  __shared__ float scL[2][100];
  int tid = threadIdx.x;
  int b2 = tid >> 7, j = tid & 127;
  int b0 = blockIdx.x * 2;
  int b = b0 + b2;
  int base = b2 * 128 + j;

  float c = cum[(size_t)b * 128 + j];
  int cap0 = lengths[b] - 4;                // capture window [cap0, cap0+3] in [0,199]

  // preload the (<=4) h_g capture values that fall in this chunk
  float hgv[4];
  #pragma unroll
  for (int d = 0; d < 4; d++) {
    int sl = cap0 + d - t0;
    hgv[d] = (sl >= 0 && sl < tc) ? bf2f(hg_seq[((size_t)sl * 1024 + b) * 128 + j]) : 0.f;
  }

  for (int seg = 0; seg < tc; seg += 100) {
    int len = (tc - seg < 100) ? (tc - seg) : 100;
    __syncthreads();                         // protect LDS reuse across segments
    // stage hl rows [seg, seg+len) : coalesced short8
    for (int f8 = tid; f8 < len * 32; f8 += 256) {
      int sl = f8 >> 5, r8 = f8 & 31;
      *(short8*)&hlL[(size_t)f8 * 8] =
          *(const short8*)(hl_seq + ((size_t)(seg + sl) * 1024 + b0) * 128 + r8 * 8);
    }
    // stage score rows (contiguous per b: layout [b][tc])
    for (int i = tid; i < 2 * len; i += 256) {
      int bb = (i >= len) ? 1 : 0;
      int sl = i - bb * len;
      scL[bb][sl] = score[(size_t)(b0 + bb) * tc + seg + sl];
    }
    __syncthreads();

    int sl = 0;
    for (; sl + 5 <= len; sl += 5) {
      float h[5], sc[5];
      #pragma unroll
      for (int k = 0; k < 5; k++) {
        h[k] = bf2f(hlL[(size_t)(sl + k) * 256 + base]);
        sc[k] = scL[b2][sl + k];
      }
      #pragma unroll
      for (int k = 0; k < 5; k++) {
        c += sc[k] * h[k];
        int d = (t0 + seg + sl + k) - cap0;
        if ((unsigned)d < 4u)
          out[((size_t)b * 4 + d) * 128 + j] = c + hgv[d];
      }
    }
    for (; sl < len; sl++) {
      c += scL[b2][sl] * bf2f(hlL[(size_t)sl * 256 + base]);
      int d = (t0 + seg + sl) - cap0;
      if ((unsigned)d < 4u)
        out[((size_t)b * 4 + d) * 128 + j] = c + hgv[d];
    }
  }
  cum[(size_t)b * 128 + j] = c;
}

// ---------------- launch ----------------
extern "C" void kernel_launch(void* const* d_in, const int* in_sizes, int n_in,
                              void* d_out, int out_size, void* d_ws, size_t ws_size,
                              hipStream_t stream)
{
  const float* x     = (const float*)d_in[0];
  const int* lengths = (const int*)d_in[1];
  const float* Wih_g = (const float*)d_in[2];
  const float* Whh_g = (const float*)d_in[3];
  const float* bih_g = (const float*)d_in[4];
  const float* bhh_g = (const float*)d_in[5];
  const float* Wih_l = (const float*)d_in[6];
  const float* Whh_l = (const float*)d_in[7];
  const float* bih_l = (const float*)d_in[8];
  const float* bhh_l = (const float*)d_in[9];
  const float* A1    = (const float*)d_in[10];
  const float* A2    = (const float*)d_in[11];
  const float* v1    = (const float*)d_in[12];
  float* out = (float*)d_out;

  // fixed region: a12 bf16 (64KB) + cum (512KB)
  const size_t fixed = 65536 + 524288;
  const int cands[6] = {50, 25, 10, 5, 2, 1};
  int tc = 0;
  for (int i = 0; i < 6; i++) {
    int T = cands[i];
    size_t need = fixed
                + 2 * (size_t)T * 1572864            // gi double-buffer (bf16, both GRUs)
                + 2 * (size_t)T * 262144             // hl, hg bf16
                + (size_t)T * 4096;                  // score fp32 [b][tc]
    if (need <= ws_size) { tc = T; break; }
  }
  if (!tc) return;

  char* wsb = (char*)d_ws;
  size_t o = 0;
  unsigned short* a12 = (unsigned short*)(wsb + o); o += 65536;
  float* cum   = (float*)(wsb + o); o += 524288;
  unsigned short* gi0 = (unsigned short*)(wsb + o); o += (size_t)tc * 1572864;
  unsigned short* gi1 = (unsigned short*)(wsb + o); o += (size_t)tc * 1572864;
  unsigned short* hl  = (unsigned short*)(wsb + o); o += (size_t)tc * 262144;
  unsigned short* hg  = (unsigned short*)(wsb + o); o += (size_t)tc * 262144;
  float* score = (float*)(wsb + o);
  // note: gi buffers precede hl/hg so the scan's one-slice gi overread stays in-bounds

  unsigned short* hl_slot = hl + (size_t)(tc - 1) * 131072;
  unsigned short* hg_slot = hg + (size_t)(tc - 1) * 131072;

  k_prep<<<512, 256, 0, stream>>>(hl_slot, hg_slot, cum, A1, A2, a12);
  k_gi<<<128, 512, 0, stream>>>(x, Wih_g, bih_g, bhh_g, Wih_l, bih_l, bhh_l, gi0, tc);

  int nch = 200 / tc;
  for (int c = 0; c < nch; c++) {
    unsigned short* rd = (c & 1) ? gi1 : gi0;
    unsigned short* wr = (c & 1) ? gi0 : gi1;
    int gtc = (c + 1 < nch) ? tc : 0;
    k_scan<<<256, 512, 0, stream>>>(x, Whh_g, bhh_g, Whh_l, bhh_l,
                                    Wih_g, bih_g, Wih_l, bih_l,
                                    hl, hg, rd, wr, tc, c * tc, gtc, (c + 1) * tc);
    k_score<<<dim3(tc, 4), 256, 0, stream>>>(hl, hg, a12, v1, score, tc);
    k_cum<<<512, 256, 0, stream>>>(score, hl, hg, lengths, cum, out, tc, c * tc);
  }
}

// Round 2
// 399.695 us; speedup vs baseline: 1.2566x; 1.2566x over previous
//
#include <hip/hip_runtime.h>
#include <stdint.h>

// NARM fused pipeline v6 for MI355X (gfx950).
//   Reverts v5's gi precompute split (measured: per-step time is NOT MFMA-bound;
//   gi HBM round-trip + per-chunk re-init was a net +100us).
//   v6 = v4 structure + software-pipelined x-MFMA: step s issues the x-chains for
//   step s+1 AFTER the h-chains, so they drain in the matrix pipe while the VALU
//   does the gate phase. Plus v_cvt_pk_bf16_f32 packing (HW RNE == old f2bf).
//   k_prep : zero carry slots + cum; cast A1/A2 -> bf16
//   k_scan : fused dual-GRU recurrence; x-MFMA pipelined one step ahead
//   k_score: grid (tc,2), 512 thr; A1/A2 bf16 staged once per block
//   k_cum  : LDS-staged cumsum of score*h_l, capture t in [L_b-4, L_b-1], +h_g

typedef __attribute__((ext_vector_type(8))) short short8;
typedef __attribute__((ext_vector_type(4))) float float4v;

// exec+LDS barrier without the full vmcnt drain of __syncthreads()
#define LDS_BARRIER() asm volatile("s_waitcnt lgkmcnt(0)\n\ts_barrier" ::: "memory")

__device__ inline float bf2f(unsigned short u){
  union { unsigned int i; float f; } v; v.i = ((unsigned int)u) << 16; return v.f;
}
__device__ inline unsigned short f2bf(float f){
  union { float f; unsigned int i; } v; v.f = f;
  unsigned int x = v.i;
  return (unsigned short)((x + 0x7fffu + ((x >> 16) & 1u)) >> 16);
}
// HW packed f32->bf16 RNE (identical rounding to f2bf); no builtin on gfx950
__device__ inline unsigned int cvt_pk_bf16(float a, float b){
  unsigned int r;
  asm("v_cvt_pk_bf16_f32 %0, %1, %2" : "=v"(r) : "v"(a), "v"(b));
  return r;
}
__device__ inline float sigm(float x){ return __builtin_amdgcn_rcpf(1.0f + __expf(-x)); }

// ---------------- K0: prep ----------------
__global__ void k_prep(unsigned short* hl_slot, unsigned short* hg_slot, float* cum,
                       const float* A1, const float* A2, unsigned short* a12)
{
  int i = blockIdx.x * blockDim.x + threadIdx.x;   // grid 512*256 = 131072
  hl_slot[i] = 0;
  hg_slot[i] = 0;
  cum[i] = 0.0f;
  if (i < 32768) {
    a12[i] = f2bf((i < 16384) ? A1[i] : A2[i - 16384]);
  }
}

// ---------------- K1: fused dual-GRU scan ----------------
// grid 128 = (64 batch-groups x 2 GRUs), block 512 (8 waves, 16 cols each).
__global__ __launch_bounds__(512, 2) void k_scan(
    const float* __restrict__ x,
    const float* __restrict__ Wih_g, const float* __restrict__ Whh_g,
    const float* __restrict__ bih_g, const float* __restrict__ bhh_g,
    const float* __restrict__ Wih_l, const float* __restrict__ Whh_l,
    const float* __restrict__ bih_l, const float* __restrict__ bhh_l,
    unsigned short* __restrict__ hl_seq, unsigned short* __restrict__ hg_seq,
    int tc, int t0)
{
  __shared__ __align__(16) unsigned short hbuf[2][16][136];
  __shared__ __align__(16) unsigned short xbuf[2][16][136];
  int tid = threadIdx.x;
  int w = tid >> 6, L = tid & 63, l15 = L & 15, q = L >> 4;
  int gru = blockIdx.x & 1;                 // 0 = g, 1 = l
  int b0 = (blockIdx.x >> 1) * 16;
  const float* Wih = gru ? Wih_l : Wih_g;
  const float* Whh = gru ? Whh_l : Whh_g;
  const float* bih = gru ? bih_l : bih_g;
  const float* bhh = gru ? bhh_l : bhh_g;
  unsigned short* myseq = gru ? hl_seq : hg_seq;

  int col = w * 16 + l15;                   // this lane's output column

  // register-resident weight B-fragments (fp32 -> bf16 once per launch)
  short8 Wi[3][4], Wh[3][4];
  #pragma unroll
  for (int G = 0; G < 3; G++) {
    int row = G * 128 + col;
    #pragma unroll
    for (int kf = 0; kf < 4; kf++) {
      const float4* p0 = (const float4*)(Wih + (size_t)row * 128 + kf * 32 + q * 8);
      const float4* p1 = (const float4*)(Whh + (size_t)row * 128 + kf * 32 + q * 8);
      float4 a0 = p0[0], a1 = p0[1], b0f = p1[0], b1f = p1[1];
      short8 si, sh;
      si[0]=(short)f2bf(a0.x); si[1]=(short)f2bf(a0.y); si[2]=(short)f2bf(a0.z); si[3]=(short)f2bf(a0.w);
      si[4]=(short)f2bf(a1.x); si[5]=(short)f2bf(a1.y); si[6]=(short)f2bf(a1.z); si[7]=(short)f2bf(a1.w);
      sh[0]=(short)f2bf(b0f.x); sh[1]=(short)f2bf(b0f.y); sh[2]=(short)f2bf(b0f.z); sh[3]=(short)f2bf(b0f.w);
      sh[4]=(short)f2bf(b1f.x); sh[5]=(short)f2bf(b1f.y); sh[6]=(short)f2bf(b1f.z); sh[7]=(short)f2bf(b1f.w);
      Wi[G][kf] = si; Wh[G][kf] = sh;
    }
  }
  float br  = bih[col]       + bhh[col];
  float bz  = bih[128 + col] + bhh[128 + col];
  float bin = bih[256 + col];               // bhh_n stays inside r*( ) per PyTorch GRU
  float bnh = bhh[256 + col];

  // init h from carry slot (zeroed by k_prep for chunk 0)
  float hold[4];
  #pragma unroll
  for (int r = 0; r < 4; r++) {
    int m = q * 4 + r;
    unsigned short u = myseq[((size_t)(tc - 1) * 1024 + b0 + m) * 128 + col];
    hold[r] = bf2f(u);
    hbuf[0][m][col] = u;
  }
  // stage x(t0) into xbuf[0]; prefetch x(t0+1) into regs
  int xrow = tid >> 5, xc4 = (tid & 31) * 4;
  {
    float4 x0 = ((const float4*)(x + ((size_t)t0 * 1024 + b0) * 128))[tid];
    *(uint2*)&xbuf[0][xrow][xc4] = make_uint2(cvt_pk_bf16(x0.x, x0.y), cvt_pk_bf16(x0.z, x0.w));
  }
  int tn = t0 + (tc > 1 ? 1 : 0);
  float4 xr = ((const float4*)(x + ((size_t)tn * 1024 + b0) * 128))[tid];
  __syncthreads();

  // prologue: x-side chains for step 0 (cx = x(t0)@Wih, consumed by step 0's gates)
  float4v cx0 = (float4v){0.f,0.f,0.f,0.f}, cx1 = cx0, cx2 = cx0;
  {
    short8 Ax[4];
    #pragma unroll
    for (int kf = 0; kf < 4; kf++) Ax[kf] = *(const short8*)&xbuf[0][l15][kf * 32 + q * 8];
    #pragma unroll
    for (int kf = 0; kf < 4; kf++) cx0 = __builtin_amdgcn_mfma_f32_16x16x32_bf16(Ax[kf], Wi[0][kf], cx0, 0,0,0);
    #pragma unroll
    for (int kf = 0; kf < 4; kf++) cx1 = __builtin_amdgcn_mfma_f32_16x16x32_bf16(Ax[kf], Wi[1][kf], cx1, 0,0,0);
    #pragma unroll
    for (int kf = 0; kf < 4; kf++) cx2 = __builtin_amdgcn_mfma_f32_16x16x32_bf16(Ax[kf], Wi[2][kf], cx2, 0,0,0);
  }
  // commit x(t0+1) into xbuf[1]; prefetch x(t0+2)
  *(uint2*)&xbuf[1][xrow][xc4] = make_uint2(cvt_pk_bf16(xr.x, xr.y), cvt_pk_bf16(xr.z, xr.w));
  {
    int t2 = t0 + (2 < tc ? 2 : tc - 1);
    xr = ((const float4*)(x + ((size_t)t2 * 1024 + b0) * 128))[tid];
  }
  LDS_BARRIER();

  // hoisted output pointer: stores at opq[r*128] with immediate offsets
  unsigned short* opq = myseq + ((size_t)(b0 + q * 4)) * 128 + col;

  // step s: pin = s&1 (h(s) buffer), pout = (s+1)&1.
  //   xbuf[pout] holds x(s+1) (committed at step s-1, barrier-protected);
  //   xbuf[pin] is dead (x(s) consumed at step s-1) -> overwritten with x(s+2).
  auto step = [&](int s, int pin, int pout) {
    short8 Ah[4], Axn[4];
    #pragma unroll
    for (int kf = 0; kf < 4; kf++) Ah[kf]  = *(const short8*)&hbuf[pin][l15][kf * 32 + q * 8];
    #pragma unroll
    for (int kf = 0; kf < 4; kf++) Axn[kf] = *(const short8*)&xbuf[pout][l15][kf * 32 + q * 8];

    // critical-path h-chains first
    float4v rh = (float4v){0.f,0.f,0.f,0.f}, zh = rh, nh = rh;
    #pragma unroll
    for (int kf = 0; kf < 4; kf++) rh = __builtin_amdgcn_mfma_f32_16x16x32_bf16(Ah[kf], Wh[0][kf], rh, 0,0,0);
    #pragma unroll
    for (int kf = 0; kf < 4; kf++) zh = __builtin_amdgcn_mfma_f32_16x16x32_bf16(Ah[kf], Wh[1][kf], zh, 0,0,0);
    #pragma unroll
    for (int kf = 0; kf < 4; kf++) nh = __builtin_amdgcn_mfma_f32_16x16x32_bf16(Ah[kf], Wh[2][kf], nh, 0,0,0);

    // background x-chains for step s+1: drain in the matrix pipe during the gate
    // VALU phase below; results consumed only at the next iteration's gates.
    float4v nx0 = (float4v){0.f,0.f,0.f,0.f}, nx1 = nx0, nx2 = nx0;
    #pragma unroll
    for (int kf = 0; kf < 4; kf++) nx0 = __builtin_amdgcn_mfma_f32_16x16x32_bf16(Axn[kf], Wi[0][kf], nx0, 0,0,0);
    #pragma unroll
    for (int kf = 0; kf < 4; kf++) nx1 = __builtin_amdgcn_mfma_f32_16x16x32_bf16(Axn[kf], Wi[1][kf], nx1, 0,0,0);
    #pragma unroll
    for (int kf = 0; kf < 4; kf++) nx2 = __builtin_amdgcn_mfma_f32_16x16x32_bf16(Axn[kf], Wi[2][kf], nx2, 0,0,0);

    // commit prefetched x(s+2) into the dead buffer; issue prefetch of x(s+3)
    *(uint2*)&xbuf[pin][xrow][xc4] = make_uint2(cvt_pk_bf16(xr.x, xr.y), cvt_pk_bf16(xr.z, xr.w));
    {
      int t3 = t0 + (s + 3 < tc ? s + 3 : tc - 1);
      xr = ((const float4*)(x + ((size_t)t3 * 1024 + b0) * 128))[tid];
    }

    // x-side gate constants for THIS step (cx computed one step ago)
    float cr[4], cz[4], cn[4];
    #pragma unroll
    for (int r = 0; r < 4; r++) { cr[r] = cx0[r] + br; cz[r] = cx1[r] + bz; cn[r] = cx2[r] + bin; }

    // gates: shared-rcp sigmoid pair + exp-based tanh
    float hnv[4];
    #pragma unroll
    for (int r = 0; r < 4; r++) {
      float er = __expf(-(rh[r] + cr[r]));
      float ez = __expf(-(zh[r] + cz[r]));
      float pr = 1.0f + er, pz = 1.0f + ez;
      float inv = __builtin_amdgcn_rcpf(pr * pz);
      float rr = pz * inv;                  // = 1/(1+er)
      float zz = pr * inv;                  // = 1/(1+ez)
      float y  = cn[r] + rr * (nh[r] + bnh);
      float em = __expf(-2.0f * y);
      float nn = 2.0f * __builtin_amdgcn_rcpf(1.0f + em) - 1.0f;   // tanh(y)
      hnv[r] = nn + zz * (hold[r] - nn);
      hold[r] = hnv[r];
    }
    // pack h via HW cvt (2 instr) and fan out to LDS + global
    unsigned int p01 = cvt_pk_bf16(hnv[0], hnv[1]);
    unsigned int p23 = cvt_pk_bf16(hnv[2], hnv[3]);
    unsigned short h0 = (unsigned short)p01, h1 = (unsigned short)(p01 >> 16);
    unsigned short h2 = (unsigned short)p23, h3 = (unsigned short)(p23 >> 16);
    hbuf[pout][q * 4 + 0][col] = h0;
    hbuf[pout][q * 4 + 1][col] = h1;
    hbuf[pout][q * 4 + 2][col] = h2;
    hbuf[pout][q * 4 + 3][col] = h3;
    opq[0]       = h0;
    opq[128]     = h1;
    opq[256]     = h2;
    opq[384]     = h3;

    cx0 = nx0; cx1 = nx1; cx2 = nx2;
    opq += 131072;                          // advance one timestep (1024*128)
    LDS_BARRIER();
  };

  int s = 0;
  for (; s + 1 < tc; s += 2) { step(s, 0, 1); step(s + 1, 1, 0); }
  if (s < tc) step(s, 0, 1);
}

// ---------------- K2: attention score ----------------
// grid (tc, 2), block 512 (8 waves); each wave: 4 b-tiles of 16 rows.
__global__ __launch_bounds__(512) void k_score(const unsigned short* __restrict__ hl_seq,
                                               const unsigned short* __restrict__ hg_seq,
                                               const unsigned short* __restrict__ a12,
                                               const float* __restrict__ v1,
                                               float* __restrict__ score, int tc)
{
  __shared__ __align__(16) unsigned short M1[128][136];
  __shared__ __align__(16) unsigned short M2[128][136];
  int tid = threadIdx.x;
  int w = tid >> 6, L = tid & 63;
  int l15 = L & 15, q = L >> 4;
  int s = blockIdx.x;
  int bhalf = blockIdx.y * 512;

  // stage A1, A2 (bf16, pre-cast by k_prep) once: 4096 short8 over 512 thr
  #pragma unroll
  for (int it = 0; it < 4; it++) {
    int f8 = it * 512 + tid;                 // 0..2047
    *(short8*)&M1[f8 >> 4][(f8 & 15) * 8] = *(const short8*)(a12 + (size_t)f8 * 8);
    *(short8*)&M2[f8 >> 4][(f8 & 15) * 8] = *(const short8*)(a12 + 16384 + (size_t)f8 * 8);
  }
  __syncthreads();

  float v1v[8];
  #pragma unroll
  for (int nt = 0; nt < 8; nt++) v1v[nt] = v1[nt * 16 + l15];

  // 4 b-tiles per wave, 1-deep fragment prefetch
  short8 Fl[4], Fg[4], Pl[4], Pg[4];
  {
    size_t base = ((size_t)s * 1024 + bhalf + (size_t)w * 16 + l15) * 128;
    #pragma unroll
    for (int kf = 0; kf < 4; kf++) {
      Fl[kf] = *(const short8*)(hl_seq + base + kf * 32 + q * 8);
      Fg[kf] = *(const short8*)(hg_seq + base + kf * 32 + q * 8);
    }
  }
  #pragma unroll
  for (int it = 0; it < 4; it++) {
    int b0 = bhalf + (it * 8 + w) * 16;
    if (it + 1 < 4) {
      size_t base = ((size_t)s * 1024 + bhalf + (size_t)((it + 1) * 8 + w) * 16 + l15) * 128;
      #pragma unroll
      for (int kf = 0; kf < 4; kf++) {
        Pl[kf] = *(const short8*)(hl_seq + base + kf * 32 + q * 8);
        Pg[kf] = *(const short8*)(hg_seq + base + kf * 32 + q * 8);
      }
    }
    float4v acc[8];
    #pragma unroll
    for (int nt = 0; nt < 8; nt++) {
      float4v a = (float4v){0.f, 0.f, 0.f, 0.f};
      #pragma unroll
      for (int kf = 0; kf < 4; kf++)
        a = __builtin_amdgcn_mfma_f32_16x16x32_bf16(
            Fl[kf], *(const short8*)&M1[nt * 16 + l15][kf * 32 + q * 8], a, 0, 0, 0);
      #pragma unroll
      for (int kf = 0; kf < 4; kf++)
        a = __builtin_amdgcn_mfma_f32_16x16x32_bf16(
            Fg[kf], *(const short8*)&M2[nt * 16 + l15][kf * 32 + q * 8], a, 0, 0, 0);
      acc[nt] = a;
    }
    float p4[4];
    #pragma unroll
    for (int r = 0; r < 4; r++) {
      float sum = 0.f;
      #pragma unroll
      for (int nt = 0; nt < 8; nt++) sum += v1v[nt] * sigm(acc[nt][r]);
      sum += __shfl_xor(sum, 1, 16);
      sum += __shfl_xor(sum, 2, 16);
      sum += __shfl_xor(sum, 4, 16);
      sum += __shfl_xor(sum, 8, 16);
      p4[r] = sum;
    }
    if (l15 == 0) {
      #pragma unroll
      for (int r = 0; r < 4; r++)
        score[(size_t)(b0 + q * 4 + r) * tc + s] = p4[r];   // layout [b][tc]
    }
    #pragma unroll
    for (int kf = 0; kf < 4; kf++) { Fl[kf] = Pl[kf]; Fg[kf] = Pg[kf]; }
  }
}

// ---------------- K3: cumsum + capture (LDS-staged) ----------------
// grid 512, block 256: 2 batch rows/block, thread = (b2, j)
__global__ __launch_bounds__(256) void k_cum(const float* __restrict__ score,
                                             const unsigned short* __restrict__ hl_seq,
                                             const unsigned short* __restrict__ hg_seq,
                                             const int* __restrict__ lengths,
                                             float* __restrict__ cum,
                                             float* __restrict__ out, int tc, int t0)
{
  __shared__ __align__(16) unsigned short hlL[100 * 256];  // [s_seg][b2*128+j]
  __shared__ float scL[2][100];
  int tid = threadIdx.x;
  int b2 = tid >> 7, j = tid & 127;
  int b0 = blockIdx.x * 2;
  int b = b0 + b2;
  int base = b2 * 128 + j;

  float c = cum[(size_t)b * 128 + j];
  int cap0 = lengths[b] - 4;                // capture window [cap0, cap0+3] in [0,199]

  // preload the (<=4) h_g capture values that fall in this chunk
  float hgv[4];
  #pragma unroll
  for (int d = 0; d < 4; d++) {
    int sl = cap0 + d - t0;
    hgv[d] = (sl >= 0 && sl < tc) ? bf2f(hg_seq[((size_t)sl * 1024 + b) * 128 + j]) : 0.f;
  }

  for (int seg = 0; seg < tc; seg += 100) {
    int len = (tc - seg < 100) ? (tc - seg) : 100;
    __syncthreads();                         // protect LDS reuse across segments
    // stage hl rows [seg, seg+len) : coalesced short8
    for (int f8 = tid; f8 < len * 32; f8 += 256) {
      int sl = f8 >> 5, r8 = f8 & 31;
      *(short8*)&hlL[(size_t)f8 * 8] =
          *(const short8*)(hl_seq + ((size_t)(seg + sl) * 1024 + b0) * 128 + r8 * 8);
    }
    // stage score rows (contiguous per b: layout [b][tc])
    for (int i = tid; i < 2 * len; i += 256) {
      int bb = (i >= len) ? 1 : 0;
      int sl = i - bb * len;
      scL[bb][sl] = score[(size_t)(b0 + bb) * tc + seg + sl];
    }
    __syncthreads();

    int sl = 0;
    for (; sl + 5 <= len; sl += 5) {
      float h[5], sc[5];
      #pragma unroll
      for (int k = 0; k < 5; k++) {
        h[k] = bf2f(hlL[(size_t)(sl + k) * 256 + base]);
        sc[k] = scL[b2][sl + k];
      }
      #pragma unroll
      for (int k = 0; k < 5; k++) {
        c += sc[k] * h[k];
        int d = (t0 + seg + sl + k) - cap0;
        if ((unsigned)d < 4u)
          out[((size_t)b * 4 + d) * 128 + j] = c + hgv[d];
      }
    }
    for (; sl < len; sl++) {
      c += scL[b2][sl] * bf2f(hlL[(size_t)sl * 256 + base]);
      int d = (t0 + seg + sl) - cap0;
      if ((unsigned)d < 4u)
        out[((size_t)b * 4 + d) * 128 + j] = c + hgv[d];
    }
  }
  cum[(size_t)b * 128 + j] = c;
}

// ---------------- launch ----------------
extern "C" void kernel_launch(void* const* d_in, const int* in_sizes, int n_in,
                              void* d_out, int out_size, void* d_ws, size_t ws_size,
                              hipStream_t stream)
{
  const float* x     = (const float*)d_in[0];
  const int* lengths = (const int*)d_in[1];
  const float* Wih_g = (const float*)d_in[2];
  const float* Whh_g = (const float*)d_in[3];
  const float* bih_g = (const float*)d_in[4];
  const float* bhh_g = (const float*)d_in[5];
  const float* Wih_l = (const float*)d_in[6];
  const float* Whh_l = (const float*)d_in[7];
  const float* bih_l = (const float*)d_in[8];
  const float* bhh_l = (const float*)d_in[9];
  const float* A1    = (const float*)d_in[10];
  const float* A2    = (const float*)d_in[11];
  const float* v1    = (const float*)d_in[12];
  float* out = (float*)d_out;

  // fixed region: a12 bf16 (64KB) + cum (512KB)
  const size_t fixed = 65536 + 524288;
  const int cands[7] = {200, 100, 50, 10, 4, 2, 1};
  int tc = 0;
  for (int i = 0; i < 7; i++) {
    int T = cands[i];
    size_t need = 2 * (size_t)T * 1024 * 128 * 2   // hl, hg bf16
                + (size_t)T * 1024 * 4             // score fp32 [b][tc]
                + fixed;
    if (need <= ws_size) { tc = T; break; }
  }
  if (!tc) return;

  char* wsb = (char*)d_ws;
  size_t o = 0;
  unsigned short* a12 = (unsigned short*)(wsb + o); o += 65536;
  float* cum   = (float*)(wsb + o); o += 524288;
  unsigned short* hl  = (unsigned short*)(wsb + o); o += (size_t)tc * 1024 * 128 * 2;
  unsigned short* hg  = (unsigned short*)(wsb + o); o += (size_t)tc * 1024 * 128 * 2;
  float* score = (float*)(wsb + o);

  unsigned short* hl_slot = hl + (size_t)(tc - 1) * 1024 * 128;
  unsigned short* hg_slot = hg + (size_t)(tc - 1) * 1024 * 128;

  k_prep<<<512, 256, 0, stream>>>(hl_slot, hg_slot, cum, A1, A2, a12);
  int nch = 200 / tc;
  for (int c = 0; c < nch; c++) {
    k_scan<<<128, 512, 0, stream>>>(x, Wih_g, Whh_g, bih_g, bhh_g,
                                    Wih_l, Whh_l, bih_l, bhh_l, hl, hg, tc, c * tc);
    k_score<<<dim3(tc, 2), 512, 0, stream>>>(hl, hg, a12, v1, score, tc);
    k_cum<<<512, 256, 0, stream>>>(score, hl, hg, lengths, cum, out, tc, c * tc);
  }
}